// Round 7
// baseline (216.317 us; speedup 1.0000x reference)
//
#include <hip/hip_runtime.h>
#include <hip/hip_bf16.h>
#include <cstdint>
#include <cstddef>

// Problem constants: T=1024, H=1024, I=512, E=16, K=4
#define T_TOK 1024
#define HDIM  1024
#define IDIM  512
#define NEXP  16
#define TOPK  4
#define CAP   1024   // per-expert entry capacity (mean 256, sd ~15.5)

typedef __bf16 bf16;
typedef __attribute__((ext_vector_type(8))) __bf16 bf16x8;
typedef __attribute__((ext_vector_type(4))) __bf16 bf16x4;
typedef __attribute__((ext_vector_type(4))) float f32x4;

__device__ __forceinline__ void lds_load16(void* lds_dst, const void* g_src) {
  __builtin_amdgcn_global_load_lds(
      (__attribute__((address_space(1))) unsigned int*)(void*)(g_src),
      (__attribute__((address_space(3))) unsigned int*)(lds_dst),
      16, 0, 0);
}

__device__ __forceinline__ bf16x4 cvt4(float4 a) {
  bf16x4 o;
  o[0] = (bf16)a.x; o[1] = (bf16)a.y; o[2] = (bf16)a.z; o[3] = (bf16)a.w;
  return o;
}
__device__ __forceinline__ bf16x8 pack2(float4 a, float4 b) {
  bf16x8 o;
  o[0] = (bf16)a.x; o[1] = (bf16)a.y; o[2] = (bf16)a.z; o[3] = (bf16)a.w;
  o[4] = (bf16)b.x; o[5] = (bf16)b.y; o[6] = (bf16)b.z; o[7] = (bf16)b.w;
  return o;
}

// ---------------- fused prep: cvt hid->bf16 (+zero row T) and routing ----------------

#define CVT_BLOCKS (T_TOK * HDIM / 4 / 256)   // 1024

__global__ void prep_kernel(const float* __restrict__ hid_f, bf16* __restrict__ hid_b,
                            const int* __restrict__ idx, const float* __restrict__ w,
                            int* __restrict__ etk, float* __restrict__ ew,
                            int* __restrict__ cntpad) {
  __shared__ int cnt;
  const int b = blockIdx.x;
  const int tid = threadIdx.x;
  if (b < CVT_BLOCKS) {
    int i = b * 256 + tid;
    float4 v = ((const float4*)hid_f)[i];
    ((bf16x4*)hid_b)[i] = cvt4(v);
    if (b == 0)  // zero pad row T
      ((bf16x4*)(hid_b + (size_t)T_TOK * HDIM))[tid] = cvt4(make_float4(0.f, 0.f, 0.f, 0.f));
    return;
  }
  const int e = b - CVT_BLOCKS;
  if (tid == 0) cnt = 0;
  __syncthreads();
  for (int j = tid; j < T_TOK * TOPK; j += blockDim.x) {
    if (idx[j] == e) {
      int slot = atomicAdd(&cnt, 1);
      if (slot < CAP) { etk[e * CAP + slot] = j; ew[e * CAP + slot] = w[j]; }
    }
  }
  __syncthreads();
  int c = cnt < CAP ? cnt : CAP;
  int p = (c + 63) & ~63;
  for (int j = c + tid; j < p; j += blockDim.x) {
    etk[e * CAP + j] = (T_TOK << 2);
    ew[e * CAP + j] = 0.f;
  }
  if (tid == 0) cntpad[e] = p;
}

// ---------------- GEMM1: hsc[entry, i] = silu(g)*u*wgt ----------------
// Block owns (e, 16 I-channels); grid (32,16)=512 all-active, no z-split (B pulled once).
// BK=128 stored as TWO 64-col sub-tiles, each with the R5-proven layout
// (128B row stride, 16B chunk c of row r at chunk c^(r&7) — zero conflicts).
// dbuf LDS, unroll-2 compile-time buffer indices (R3-proven). LDS 48KB.

__global__ __launch_bounds__(256, 2) void gemm1_kernel(
    const bf16* __restrict__ hid,    // [(T+1),H] bf16, row T zeroed
    const float* __restrict__ gup,   // [E,2I,H] fp32
    const int* __restrict__ etk, const float* __restrict__ ew,
    const int* __restrict__ cntpad,
    bf16* __restrict__ hsc) {        // [E*CAP, I] bf16
  __shared__ __align__(16) bf16 As[2][2][64 * 64];   // 32 KB
  __shared__ __align__(16) bf16 BgS[2][2][16 * 64];  // 8 KB
  __shared__ __align__(16) bf16 BuS[2][2][16 * 64];  // 8 KB
  const int e  = blockIdx.y;
  const int trips = cntpad[e] >> 6;
  const int n0 = blockIdx.x * 16;
  const int ebase = e * CAP;
  const int tid = threadIdx.x, lane = tid & 63, wid = tid >> 6;
  const int wm = wid * 16;
  const int lcol = lane & 15, lquad = lane >> 4;
  // A async staging (R5 pattern): row srow (0..31, +32 for 2nd), chunk tid&7;
  // source col compensates the xor swizzle.
  const int srow = tid >> 3;
  const int swz  = ((tid & 7) ^ (srow & 7)) * 8;
  // B staging (R5 pattern): 16 rows, br=tid>>4, bc=(tid&15)*4 fp32; half-chunk writes
  const int br = tid >> 4;
  const int bc = (tid & 15) * 4;
  const int wb = (((bc >> 3) ^ (br & 7)) * 8) + (bc & 7);
  const float* gBg = gup + (size_t)e * (2 * IDIM) * HDIM + (size_t)(n0 + br) * HDIM + bc;
  const float* gBu = gBg + (size_t)IDIM * HDIM;

  for (int m = 0; m < trips; ++m) {
    const int mb = ebase + m * 64;
    const int t0 = etk[mb + srow] >> 2;
    const int t1 = etk[mb + srow + 32] >> 2;
    const bf16* gA0 = hid + (size_t)t0 * HDIM + swz;
    const bf16* gA1 = hid + (size_t)t1 * HDIM + swz;
    float wgt[4];
#pragma unroll
    for (int rr = 0; rr < 4; ++rr) wgt[rr] = ew[mb + wm + lquad * 4 + rr];

    f32x4 aG = f32x4{0.f, 0.f, 0.f, 0.f};
    f32x4 aU = f32x4{0.f, 0.f, 0.f, 0.f};

    // prologue: stage k=0 into buf0 (prev trip's last iter only touches buf1 post-barrier)
#pragma unroll
    for (int s = 0; s < 2; ++s) {
      lds_load16(&As[0][s][tid * 8],        gA0 + s * 64);
      lds_load16(&As[0][s][tid * 8 + 2048], gA1 + s * 64);
      float4 vg = *(const float4*)(gBg + s * 64);
      float4 vu = *(const float4*)(gBu + s * 64);
      *(bf16x4*)&BgS[0][s][br * 64 + wb] = cvt4(vg);
      *(bf16x4*)&BuS[0][s][br * 64 + wb] = cvt4(vu);
    }
#pragma unroll 2
    for (int k = 0; k < 8; ++k) {
      const int cur = k & 1, nxt = cur ^ 1;
      __syncthreads();   // buf[cur] staged & visible
      float4 g[2], u[2];
      if (k < 7) {       // prefetch k+1 into buf[nxt] (free after this barrier)
        const int ko = (k + 1) * 128;
#pragma unroll
        for (int s = 0; s < 2; ++s) {
          lds_load16(&As[nxt][s][tid * 8],        gA0 + ko + s * 64);
          lds_load16(&As[nxt][s][tid * 8 + 2048], gA1 + ko + s * 64);
          g[s] = *(const float4*)(gBg + ko + s * 64);
          u[s] = *(const float4*)(gBu + ko + s * 64);
        }
      }
      // compute buf[cur]: 4 ks-steps over 2 sub-tiles
#pragma unroll
      for (int ks = 0; ks < 4; ++ks) {
        const int sub = ks >> 1;
        const int lch = (ks & 1) * 4 + lquad;
        const int ar = wm + lcol;
        bf16x8 af = *(const bf16x8*)&As[cur][sub][ar * 64 + ((lch ^ (ar & 7)) * 8)];
        bf16x8 bg = *(const bf16x8*)&BgS[cur][sub][lcol * 64 + ((lch ^ (lcol & 7)) * 8)];
        bf16x8 bu = *(const bf16x8*)&BuS[cur][sub][lcol * 64 + ((lch ^ (lcol & 7)) * 8)];
        aG = __builtin_amdgcn_mfma_f32_16x16x32_bf16(af, bg, aG, 0, 0, 0);
        aU = __builtin_amdgcn_mfma_f32_16x16x32_bf16(af, bu, aU, 0, 0, 0);
      }
      if (k < 7) {  // B reg->LDS after compute
#pragma unroll
        for (int s = 0; s < 2; ++s) {
          *(bf16x4*)&BgS[nxt][s][br * 64 + wb] = cvt4(g[s]);
          *(bf16x4*)&BuS[nxt][s][br * 64 + wb] = cvt4(u[s]);
        }
      }
    }
    // epilogue: C/D col=lane&15, row=lquad*4+rr
#pragma unroll
    for (int rr = 0; rr < 4; ++rr) {
      const int erow = m * 64 + wm + lquad * 4 + rr;
      float g = aG[rr], u = aU[rr];
      float s = g / (1.f + __expf(-g));
      hsc[(size_t)(ebase + erow) * IDIM + n0 + lcol] = (bf16)(s * u * wgt[rr]);
    }
  }
}

// ---------------- GEMM2: slab[k][tok,h] = hsc[entry,:] . down[e,h,:] ----------------
// Block owns (e, 32 H-channels); grid (32,16)=512, no z. BK=128 as two 64-col
// sub-tiles (R5 layouts), dbuf, K=512 -> 4 iters/trip. Plain scatter stores.

__global__ __launch_bounds__(256, 2) void gemm2_kernel(
    const bf16* __restrict__ hsc,    // [E*CAP, I] bf16
    const float* __restrict__ down,  // [E,H,I] fp32
    const int* __restrict__ etk, const int* __restrict__ cntpad,
    float* __restrict__ slabs) {     // [4][(T+1)][H] fp32
  __shared__ __align__(16) bf16 As[2][2][64 * 64];   // 32 KB
  __shared__ __align__(16) bf16 Bs[2][2][32 * 64];   // 16 KB
  const int e  = blockIdx.y;
  const int trips = cntpad[e] >> 6;
  const int n0 = blockIdx.x * 32;
  const int ebase = e * CAP;
  const int tid = threadIdx.x, lane = tid & 63, wid = tid >> 6;
  const int wm = wid * 16;
  const int lcol = lane & 15, lquad = lane >> 4;
  const int srow = tid >> 3;
  const int swz  = ((tid & 7) ^ (srow & 7)) * 8;
  // B staging (R5 pattern): 32 rows, btr=tid>>3, c0=(tid&7)*8 fp32; full-chunk writes
  const int btr = tid >> 3;
  const int c0  = (tid & 7) * 8;
  const int wbk = ((tid & 7) ^ (btr & 7)) * 8;
  const float* gB = down + (size_t)e * HDIM * IDIM + (size_t)(n0 + btr) * IDIM + c0;

  for (int m = 0; m < trips; ++m) {
    const int mb = ebase + m * 64;
    int tks[4];
#pragma unroll
    for (int rr = 0; rr < 4; ++rr) tks[rr] = etk[mb + wm + lquad * 4 + rr];
    const bf16* gA = hsc + (size_t)(mb + srow) * IDIM + swz;

    f32x4 acc0 = f32x4{0.f, 0.f, 0.f, 0.f};
    f32x4 acc1 = f32x4{0.f, 0.f, 0.f, 0.f};

    // prologue: k=0 -> buf0
#pragma unroll
    for (int s = 0; s < 2; ++s) {
      lds_load16(&As[0][s][tid * 8],        gA + s * 64);
      lds_load16(&As[0][s][tid * 8 + 2048], gA + s * 64 + (size_t)32 * IDIM);
      float4 v0 = *(const float4*)(gB + s * 64);
      float4 v1 = *(const float4*)(gB + s * 64 + 4);
      *(bf16x8*)&Bs[0][s][btr * 64 + wbk] = pack2(v0, v1);
    }
#pragma unroll 2
    for (int k = 0; k < 4; ++k) {
      const int cur = k & 1, nxt = cur ^ 1;
      __syncthreads();
      float4 v0[2], v1[2];
      if (k < 3) {
        const int ko = (k + 1) * 128;
#pragma unroll
        for (int s = 0; s < 2; ++s) {
          lds_load16(&As[nxt][s][tid * 8],        gA + ko + s * 64);
          lds_load16(&As[nxt][s][tid * 8 + 2048], gA + ko + s * 64 + (size_t)32 * IDIM);
          v0[s] = *(const float4*)(gB + ko + s * 64);
          v1[s] = *(const float4*)(gB + ko + s * 64 + 4);
        }
      }
#pragma unroll
      for (int ks = 0; ks < 4; ++ks) {
        const int sub = ks >> 1;
        const int lch = (ks & 1) * 4 + lquad;
        const int ar = wm + lcol;
        bf16x8 af = *(const bf16x8*)&As[cur][sub][ar * 64 + ((lch ^ (ar & 7)) * 8)];
        const int br0 = lcol, br1 = 16 + lcol;
        bf16x8 b0 = *(const bf16x8*)&Bs[cur][sub][br0 * 64 + ((lch ^ (br0 & 7)) * 8)];
        bf16x8 b1 = *(const bf16x8*)&Bs[cur][sub][br1 * 64 + ((lch ^ (br1 & 7)) * 8)];
        acc0 = __builtin_amdgcn_mfma_f32_16x16x32_bf16(af, b0, acc0, 0, 0, 0);
        acc1 = __builtin_amdgcn_mfma_f32_16x16x32_bf16(af, b1, acc1, 0, 0, 0);
      }
      if (k < 3) {
#pragma unroll
        for (int s = 0; s < 2; ++s)
          *(bf16x8*)&Bs[nxt][s][btr * 64 + wbk] = pack2(v0[s], v1[s]);
      }
    }
    // epilogue: plain scatter stores (each (t,k) slab row written once)
#pragma unroll
    for (int rr = 0; rr < 4; ++rr) {
      const int tok = tks[rr] >> 2, kslot = tks[rr] & 3;
      float* orow = slabs + ((size_t)kslot * (T_TOK + 1) + tok) * HDIM + n0;
      orow[lcol]      = acc0[rr];
      orow[16 + lcol] = acc1[rr];
    }
  }
}

// ---------------- reduce: out = sum of 4 slabs ----------------

__global__ void reduce_kernel(const float* __restrict__ slabs, float* __restrict__ out) {
  const size_t stride = (size_t)(T_TOK + 1) * HDIM;
  int i = blockIdx.x * blockDim.x + threadIdx.x;
  float4 a = ((const float4*)slabs)[i];
  float4 b = ((const float4*)(slabs + stride))[i];
  float4 c = ((const float4*)(slabs + 2 * stride))[i];
  float4 d = ((const float4*)(slabs + 3 * stride))[i];
  float4 o;
  o.x = a.x + b.x + c.x + d.x;
  o.y = a.y + b.y + c.y + d.y;
  o.z = a.z + b.z + c.z + d.z;
  o.w = a.w + b.w + c.w + d.w;
  ((float4*)out)[i] = o;
}

// ---------------- launch ----------------

extern "C" void kernel_launch(void* const* d_in, const int* in_sizes, int n_in,
                              void* d_out, int out_size, void* d_ws, size_t ws_size,
                              hipStream_t stream) {
  const float* hid_f  = (const float*)d_in[0];
  const int*   idx    = (const int*)d_in[1];
  const float* tw     = (const float*)d_in[2];
  const float* gup_f  = (const float*)d_in[3];
  const float* down_f = (const float*)d_in[4];
  float* out = (float*)d_out;

  uint8_t* ws = (uint8_t*)d_ws;
  size_t off = 0;
  bf16* hid_b = (bf16*)(ws + off);   off += (size_t)(T_TOK + 1) * HDIM * 2;
  int*  etk   = (int*)(ws + off);    off += (size_t)NEXP * CAP * 4;
  float* ewt  = (float*)(ws + off);  off += (size_t)NEXP * CAP * 4;
  int* cntpad = (int*)(ws + off);    off += 256;
  bf16* hsc   = (bf16*)(ws + off);   off += (size_t)NEXP * CAP * IDIM * 2;
  float* slabs = (float*)(ws + off); // 4*(T+1)*H*4 ≈ 16.8 MB

  prep_kernel<<<dim3(CVT_BLOCKS + NEXP), dim3(256), 0, stream>>>(
      hid_f, hid_b, idx, tw, etk, ewt, cntpad);
  gemm1_kernel<<<dim3(IDIM / 16, NEXP), dim3(256), 0, stream>>>(
      hid_b, gup_f, etk, ewt, cntpad, hsc);
  gemm2_kernel<<<dim3(HDIM / 32, NEXP), dim3(256), 0, stream>>>(
      hsc, down_f, etk, cntpad, slabs);
  reduce_kernel<<<dim3(T_TOK * HDIM / 4 / 256), dim3(256), 0, stream>>>(slabs, out);
}

// Round 8
// 191.852 us; speedup vs baseline: 1.1275x; 1.1275x over previous
//
#include <hip/hip_runtime.h>
#include <hip/hip_bf16.h>
#include <cstdint>
#include <cstddef>

// Problem constants: T=1024, H=1024, I=512, E=16, K=4
#define T_TOK 1024
#define HDIM  1024
#define IDIM  512
#define NEXP  16
#define TOPK  4
#define CAP   1024   // per-expert entry capacity
#define GROUP 5      // register-resident 64-entry tiles per pass (320 >= mean+4sd)

typedef __bf16 bf16;
typedef __attribute__((ext_vector_type(8))) __bf16 bf16x8;
typedef __attribute__((ext_vector_type(4))) __bf16 bf16x4;
typedef __attribute__((ext_vector_type(4))) float f32x4;

__device__ __forceinline__ void lds_load16(void* lds_dst, const void* g_src) {
  __builtin_amdgcn_global_load_lds(
      (__attribute__((address_space(1))) unsigned int*)(void*)(g_src),
      (__attribute__((address_space(3))) unsigned int*)(lds_dst),
      16, 0, 0);
}

__device__ __forceinline__ bf16x4 cvt4(float4 a) {
  bf16x4 o;
  o[0] = (bf16)a.x; o[1] = (bf16)a.y; o[2] = (bf16)a.z; o[3] = (bf16)a.w;
  return o;
}
__device__ __forceinline__ bf16x8 pack2(float4 a, float4 b) {
  bf16x8 o;
  o[0] = (bf16)a.x; o[1] = (bf16)a.y; o[2] = (bf16)a.z; o[3] = (bf16)a.w;
  o[4] = (bf16)b.x; o[5] = (bf16)b.y; o[6] = (bf16)b.z; o[7] = (bf16)b.w;
  return o;
}

// ---------------- fused prep: cvt hid->bf16 (+zero row T) and routing ----------------

#define CVT_BLOCKS (T_TOK * HDIM / 4 / 256)   // 1024

__global__ void prep_kernel(const float* __restrict__ hid_f, bf16* __restrict__ hid_b,
                            const int* __restrict__ idx, const float* __restrict__ w,
                            int* __restrict__ etk, float* __restrict__ ew,
                            int* __restrict__ cntpad) {
  __shared__ int cnt;
  const int b = blockIdx.x;
  const int tid = threadIdx.x;
  if (b < CVT_BLOCKS) {
    int i = b * 256 + tid;
    float4 v = ((const float4*)hid_f)[i];
    ((bf16x4*)hid_b)[i] = cvt4(v);
    if (b == 0)  // zero pad row T
      ((bf16x4*)(hid_b + (size_t)T_TOK * HDIM))[tid] = cvt4(make_float4(0.f, 0.f, 0.f, 0.f));
    return;
  }
  const int e = b - CVT_BLOCKS;
  if (tid == 0) cnt = 0;
  __syncthreads();
  for (int j = tid; j < T_TOK * TOPK; j += blockDim.x) {
    if (idx[j] == e) {
      int slot = atomicAdd(&cnt, 1);
      if (slot < CAP) { etk[e * CAP + slot] = j; ew[e * CAP + slot] = w[j]; }
    }
  }
  __syncthreads();
  int c = cnt < CAP ? cnt : CAP;
  int p = (c + 63) & ~63;
  for (int j = c + tid; j < p; j += blockDim.x) {
    etk[e * CAP + j] = (T_TOK << 2);
    ew[e * CAP + j] = 0.f;
  }
  if (tid == 0) cntpad[e] = p;
}

// ---------------- GEMM1: hsc[entry, i] = silu(g)*u*wgt ----------------
// K-outermost, weights read ONCE: block owns (e, 16 I-channels); all GROUP m-tiles
// register-resident (aG[5], aU[5]). Per k-iter: 5 async A-tiles + B via regs->LDS,
// 2-barrier body (R5-proven), R5-proven swizzled layouts (zero conflicts).
// Grid (32,16)=512 all-active. LDS = 5*8KB A + 2+2KB B = 44KB.

__global__ __launch_bounds__(256, 2) void gemm1_kernel(
    const bf16* __restrict__ hid,    // [(T+1),H] bf16, row T zeroed
    const float* __restrict__ gup,   // [E,2I,H] fp32
    const int* __restrict__ etk, const float* __restrict__ ew,
    const int* __restrict__ cntpad,
    bf16* __restrict__ hsc) {        // [E*CAP, I] bf16
  __shared__ __align__(16) bf16 As[GROUP][64 * 64];  // 40 KB
  __shared__ __align__(16) bf16 BgS[16 * 64];        // 2 KB
  __shared__ __align__(16) bf16 BuS[16 * 64];        // 2 KB
  const int e  = blockIdx.y;
  const int trips = cntpad[e] >> 6;
  const int n0 = blockIdx.x * 16;
  const int ebase = e * CAP;
  const int tid = threadIdx.x, lane = tid & 63, wid = tid >> 6;
  const int wm = wid * 16;
  const int lcol = lane & 15, lquad = lane >> 4;
  // A async staging (R5): rows srow, srow+32; source col compensates swizzle
  const int srow = tid >> 3;
  const int swz  = ((tid & 7) ^ (srow & 7)) * 8;
  // B staging (R5): 16 rows, br=tid>>4, bc=(tid&15)*4 fp32; half-chunk writes
  const int br = tid >> 4;
  const int bc = (tid & 15) * 4;
  const int wb = (((bc >> 3) ^ (br & 7)) * 8) + (bc & 7);
  const float* gBg = gup + (size_t)e * (2 * IDIM) * HDIM + (size_t)(n0 + br) * HDIM + bc;
  const float* gBu = gBg + (size_t)IDIM * HDIM;

  for (int mg = 0; mg < trips; mg += GROUP) {
    const int tg = trips - mg < GROUP ? trips - mg : GROUP;
    const bf16 *gA0[GROUP], *gA1[GROUP];
#pragma unroll
    for (int mt = 0; mt < GROUP; ++mt)
      if (mt < tg) {
        const int mb = ebase + (mg + mt) * 64;
        gA0[mt] = hid + (size_t)(etk[mb + srow] >> 2) * HDIM + swz;
        gA1[mt] = hid + (size_t)(etk[mb + srow + 32] >> 2) * HDIM + swz;
      }
    f32x4 aG[GROUP], aU[GROUP];
#pragma unroll
    for (int mt = 0; mt < GROUP; ++mt) {
      aG[mt] = f32x4{0.f, 0.f, 0.f, 0.f};
      aU[mt] = f32x4{0.f, 0.f, 0.f, 0.f};
    }
    for (int k = 0; k < HDIM / 64; ++k) {
      float4 vg = *(const float4*)(gBg + k * 64);   // reg-only, before barrier
      float4 vu = *(const float4*)(gBu + k * 64);
      __syncthreads();                              // prev compute done
#pragma unroll
      for (int mt = 0; mt < GROUP; ++mt)
        if (mt < tg) {
          lds_load16(&As[mt][tid * 8],        gA0[mt] + k * 64);
          lds_load16(&As[mt][tid * 8 + 2048], gA1[mt] + k * 64);
        }
      *(bf16x4*)&BgS[br * 64 + wb] = cvt4(vg);
      *(bf16x4*)&BuS[br * 64 + wb] = cvt4(vu);
      __syncthreads();                              // staging visible (vmcnt drained)
#pragma unroll
      for (int ks = 0; ks < 2; ++ks) {
        const int lch = ks * 4 + lquad;
        bf16x8 bg = *(const bf16x8*)&BgS[lcol * 64 + ((lch ^ (lcol & 7)) * 8)];
        bf16x8 bu = *(const bf16x8*)&BuS[lcol * 64 + ((lch ^ (lcol & 7)) * 8)];
        const int ar = wm + lcol;
        const int aoff = ar * 64 + ((lch ^ (ar & 7)) * 8);
#pragma unroll
        for (int mt = 0; mt < GROUP; ++mt)
          if (mt < tg) {
            bf16x8 af = *(const bf16x8*)&As[mt][aoff];
            aG[mt] = __builtin_amdgcn_mfma_f32_16x16x32_bf16(af, bg, aG[mt], 0, 0, 0);
            aU[mt] = __builtin_amdgcn_mfma_f32_16x16x32_bf16(af, bu, aU[mt], 0, 0, 0);
          }
      }
    }
    // epilogue: C/D col=lane&15, row=lquad*4+rr
#pragma unroll
    for (int mt = 0; mt < GROUP; ++mt)
      if (mt < tg) {
#pragma unroll
        for (int rr = 0; rr < 4; ++rr) {
          const int erow = (mg + mt) * 64 + wm + lquad * 4 + rr;
          const float wgt = ew[ebase + erow];
          float g = aG[mt][rr], u = aU[mt][rr];
          float s = g / (1.f + __expf(-g));
          hsc[(size_t)(ebase + erow) * IDIM + n0 + lcol] = (bf16)(s * u * wgt);
        }
      }
  }
}

// ---------------- GEMM2: slab[k][tok,h] = hsc[entry,:] . down[e,h,:] ----------------
// Same inversion: block owns (e, 32 H-channels); down slice (64 KB) read once;
// GROUP m-tiles register-resident (acc[5][2]). K=512 -> 8 iters. Plain scatter stores.

__global__ __launch_bounds__(256, 2) void gemm2_kernel(
    const bf16* __restrict__ hsc,    // [E*CAP, I] bf16
    const float* __restrict__ down,  // [E,H,I] fp32
    const int* __restrict__ etk, const int* __restrict__ cntpad,
    float* __restrict__ slabs) {     // [4][(T+1)][H] fp32
  __shared__ __align__(16) bf16 As[GROUP][64 * 64];  // 40 KB
  __shared__ __align__(16) bf16 Bs[32 * 64];         // 4 KB
  const int e  = blockIdx.y;
  const int trips = cntpad[e] >> 6;
  const int n0 = blockIdx.x * 32;
  const int ebase = e * CAP;
  const int tid = threadIdx.x, lane = tid & 63, wid = tid >> 6;
  const int wm = wid * 16;
  const int lcol = lane & 15, lquad = lane >> 4;
  const int srow = tid >> 3;
  const int swz  = ((tid & 7) ^ (srow & 7)) * 8;
  // B staging (R5): 32 rows, btr=tid>>3, c0=(tid&7)*8 fp32; full-chunk writes
  const int btr = tid >> 3;
  const int c0  = (tid & 7) * 8;
  const int wbk = ((tid & 7) ^ (btr & 7)) * 8;
  const float* gB = down + (size_t)e * HDIM * IDIM + (size_t)(n0 + btr) * IDIM + c0;

  for (int mg = 0; mg < trips; mg += GROUP) {
    const int tg = trips - mg < GROUP ? trips - mg : GROUP;
    f32x4 acc[GROUP][2];
#pragma unroll
    for (int mt = 0; mt < GROUP; ++mt) {
      acc[mt][0] = f32x4{0.f, 0.f, 0.f, 0.f};
      acc[mt][1] = f32x4{0.f, 0.f, 0.f, 0.f};
    }
    for (int k = 0; k < IDIM / 64; ++k) {
      float4 v0 = *(const float4*)(gB + k * 64);
      float4 v1 = *(const float4*)(gB + k * 64 + 4);
      __syncthreads();
#pragma unroll
      for (int mt = 0; mt < GROUP; ++mt)
        if (mt < tg) {
          const bf16* gA = hsc + (size_t)(ebase + (mg + mt) * 64 + srow) * IDIM + k * 64 + swz;
          lds_load16(&As[mt][tid * 8],        gA);
          lds_load16(&As[mt][tid * 8 + 2048], gA + (size_t)32 * IDIM);
        }
      *(bf16x8*)&Bs[btr * 64 + wbk] = pack2(v0, v1);
      __syncthreads();
#pragma unroll
      for (int ks = 0; ks < 2; ++ks) {
        const int lch = ks * 4 + lquad;
        const int br0 = lcol, br1 = 16 + lcol;
        bf16x8 b0 = *(const bf16x8*)&Bs[br0 * 64 + ((lch ^ (br0 & 7)) * 8)];
        bf16x8 b1 = *(const bf16x8*)&Bs[br1 * 64 + ((lch ^ (br1 & 7)) * 8)];
        const int ar = wm + lcol;
        const int aoff = ar * 64 + ((lch ^ (ar & 7)) * 8);
#pragma unroll
        for (int mt = 0; mt < GROUP; ++mt)
          if (mt < tg) {
            bf16x8 af = *(const bf16x8*)&As[mt][aoff];
            acc[mt][0] = __builtin_amdgcn_mfma_f32_16x16x32_bf16(af, b0, acc[mt][0], 0, 0, 0);
            acc[mt][1] = __builtin_amdgcn_mfma_f32_16x16x32_bf16(af, b1, acc[mt][1], 0, 0, 0);
          }
      }
    }
    // epilogue: plain scatter stores (each (t,k) slab row written once)
#pragma unroll
    for (int mt = 0; mt < GROUP; ++mt)
      if (mt < tg) {
#pragma unroll
        for (int rr = 0; rr < 4; ++rr) {
          const int tk = etk[ebase + (mg + mt) * 64 + wm + lquad * 4 + rr];
          const int tok = tk >> 2, kslot = tk & 3;
          float* orow = slabs + ((size_t)kslot * (T_TOK + 1) + tok) * HDIM + n0;
          orow[lcol]      = acc[mt][0][rr];
          orow[16 + lcol] = acc[mt][1][rr];
        }
      }
  }
}

// ---------------- reduce: out = sum of 4 slabs ----------------

__global__ void reduce_kernel(const float* __restrict__ slabs, float* __restrict__ out) {
  const size_t stride = (size_t)(T_TOK + 1) * HDIM;
  int i = blockIdx.x * blockDim.x + threadIdx.x;
  float4 a = ((const float4*)slabs)[i];
  float4 b = ((const float4*)(slabs + stride))[i];
  float4 c = ((const float4*)(slabs + 2 * stride))[i];
  float4 d = ((const float4*)(slabs + 3 * stride))[i];
  float4 o;
  o.x = a.x + b.x + c.x + d.x;
  o.y = a.y + b.y + c.y + d.y;
  o.z = a.z + b.z + c.z + d.z;
  o.w = a.w + b.w + c.w + d.w;
  ((float4*)out)[i] = o;
}

// ---------------- launch ----------------

extern "C" void kernel_launch(void* const* d_in, const int* in_sizes, int n_in,
                              void* d_out, int out_size, void* d_ws, size_t ws_size,
                              hipStream_t stream) {
  const float* hid_f  = (const float*)d_in[0];
  const int*   idx    = (const int*)d_in[1];
  const float* tw     = (const float*)d_in[2];
  const float* gup_f  = (const float*)d_in[3];
  const float* down_f = (const float*)d_in[4];
  float* out = (float*)d_out;

  uint8_t* ws = (uint8_t*)d_ws;
  size_t off = 0;
  bf16* hid_b = (bf16*)(ws + off);   off += (size_t)(T_TOK + 1) * HDIM * 2;
  int*  etk   = (int*)(ws + off);    off += (size_t)NEXP * CAP * 4;
  float* ewt  = (float*)(ws + off);  off += (size_t)NEXP * CAP * 4;
  int* cntpad = (int*)(ws + off);    off += 256;
  bf16* hsc   = (bf16*)(ws + off);   off += (size_t)NEXP * CAP * IDIM * 2;
  float* slabs = (float*)(ws + off); // 4*(T+1)*H*4 ≈ 16.8 MB

  prep_kernel<<<dim3(CVT_BLOCKS + NEXP), dim3(256), 0, stream>>>(
      hid_f, hid_b, idx, tw, etk, ewt, cntpad);
  gemm1_kernel<<<dim3(IDIM / 16, NEXP), dim3(256), 0, stream>>>(
      hid_b, gup_f, etk, ewt, cntpad, hsc);
  gemm2_kernel<<<dim3(HDIM / 32, NEXP), dim3(256), 0, stream>>>(
      hsc, down_f, etk, cntpad, slabs);
  reduce_kernel<<<dim3(T_TOK * HDIM / 4 / 256), dim3(256), 0, stream>>>(slabs, out);
}

// Round 9
// 190.797 us; speedup vs baseline: 1.1338x; 1.0055x over previous
//
#include <hip/hip_runtime.h>
#include <hip/hip_bf16.h>
#include <cstdint>
#include <cstddef>

// Problem constants: T=1024, H=1024, I=512, E=16, K=4
#define T_TOK 1024
#define HDIM  1024
#define IDIM  512
#define NEXP  16
#define TOPK  4
#define CAP   1024   // per-expert entry capacity
#define GROUP 3      // register-resident m-tiles per z-parity (covers trips<=6)

typedef __bf16 bf16;
typedef __attribute__((ext_vector_type(8))) __bf16 bf16x8;
typedef __attribute__((ext_vector_type(4))) __bf16 bf16x4;
typedef __attribute__((ext_vector_type(4))) float f32x4;

__device__ __forceinline__ void lds_load16(void* lds_dst, const void* g_src) {
  __builtin_amdgcn_global_load_lds(
      (__attribute__((address_space(1))) unsigned int*)(void*)(g_src),
      (__attribute__((address_space(3))) unsigned int*)(lds_dst),
      16, 0, 0);
}

__device__ __forceinline__ bf16x4 cvt4(float4 a) {
  bf16x4 o;
  o[0] = (bf16)a.x; o[1] = (bf16)a.y; o[2] = (bf16)a.z; o[3] = (bf16)a.w;
  return o;
}

// ---------------- fused prep: cvt hid->bf16 (+zero row T) and routing ----------------

#define CVT_BLOCKS (T_TOK * HDIM / 4 / 256)   // 1024

__global__ void prep_kernel(const float* __restrict__ hid_f, bf16* __restrict__ hid_b,
                            const int* __restrict__ idx, const float* __restrict__ w,
                            int* __restrict__ etk, float* __restrict__ ew,
                            int* __restrict__ cntpad) {
  __shared__ int cnt;
  const int b = blockIdx.x;
  const int tid = threadIdx.x;
  if (b < CVT_BLOCKS) {
    int i = b * 256 + tid;
    float4 v = ((const float4*)hid_f)[i];
    ((bf16x4*)hid_b)[i] = cvt4(v);
    if (b == 0)  // zero pad row T
      ((bf16x4*)(hid_b + (size_t)T_TOK * HDIM))[tid] = cvt4(make_float4(0.f, 0.f, 0.f, 0.f));
    return;
  }
  const int e = b - CVT_BLOCKS;
  if (tid == 0) cnt = 0;
  __syncthreads();
  for (int j = tid; j < T_TOK * TOPK; j += blockDim.x) {
    if (idx[j] == e) {
      int slot = atomicAdd(&cnt, 1);
      if (slot < CAP) { etk[e * CAP + slot] = j; ew[e * CAP + slot] = w[j]; }
    }
  }
  __syncthreads();
  int c = cnt < CAP ? cnt : CAP;
  int p = (c + 63) & ~63;
  for (int j = c + tid; j < p; j += blockDim.x) {
    etk[e * CAP + j] = (T_TOK << 2);
    ew[e * CAP + j] = 0.f;
  }
  if (tid == 0) cntpad[e] = p;
}

// ---------------- GEMM1: hsc[entry, i] = silu(g)*u*wgt ----------------
// K-outermost, weights once per block. z in {0,1} takes m-tiles of parity z
// (GROUP=3 register accumulator sets). Grid (32,16,2)=1024 all-active, 4 blocks/CU
// (LDS 28KB). 2-barrier single-buffer body, R5-proven swizzled layouts.

__global__ __launch_bounds__(256, 4) void gemm1_kernel(
    const bf16* __restrict__ hid,    // [(T+1),H] bf16, row T zeroed
    const float* __restrict__ gup,   // [E,2I,H] fp32
    const int* __restrict__ etk, const float* __restrict__ ew,
    const int* __restrict__ cntpad,
    bf16* __restrict__ hsc) {        // [E*CAP, I] bf16
  __shared__ __align__(16) bf16 As[GROUP][64 * 64];  // 24 KB
  __shared__ __align__(16) bf16 BgS[16 * 64];        // 2 KB
  __shared__ __align__(16) bf16 BuS[16 * 64];        // 2 KB
  const int e  = blockIdx.y;
  const int z  = blockIdx.z;
  const int trips = cntpad[e] >> 6;
  const int n0 = blockIdx.x * 16;
  const int ebase = e * CAP;
  const int tid = threadIdx.x, lane = tid & 63, wid = tid >> 6;
  const int wm = wid * 16;
  const int lcol = lane & 15, lquad = lane >> 4;
  // A async staging (R5): rows srow, srow+32; source col compensates swizzle
  const int srow = tid >> 3;
  const int swz  = ((tid & 7) ^ (srow & 7)) * 8;
  // B staging (R5): 16 rows, br=tid>>4, bc=(tid&15)*4 fp32; half-chunk writes
  const int br = tid >> 4;
  const int bc = (tid & 15) * 4;
  const int wb = (((bc >> 3) ^ (br & 7)) * 8) + (bc & 7);
  const float* gBg = gup + (size_t)e * (2 * IDIM) * HDIM + (size_t)(n0 + br) * HDIM + bc;
  const float* gBu = gBg + (size_t)IDIM * HDIM;

  for (int mg = z; mg < trips; mg += 2 * GROUP) {
    int tg = (trips - mg + 1) >> 1;            // tiles of this parity remaining
    if (tg > GROUP) tg = GROUP;
    const bf16 *gA0[GROUP], *gA1[GROUP];
#pragma unroll
    for (int mt = 0; mt < GROUP; ++mt)
      if (mt < tg) {
        const int mb = ebase + (mg + 2 * mt) * 64;
        gA0[mt] = hid + (size_t)(etk[mb + srow] >> 2) * HDIM + swz;
        gA1[mt] = hid + (size_t)(etk[mb + srow + 32] >> 2) * HDIM + swz;
      }
    f32x4 aG[GROUP], aU[GROUP];
#pragma unroll
    for (int mt = 0; mt < GROUP; ++mt) {
      aG[mt] = f32x4{0.f, 0.f, 0.f, 0.f};
      aU[mt] = f32x4{0.f, 0.f, 0.f, 0.f};
    }
    for (int k = 0; k < HDIM / 64; ++k) {
      float4 vg = *(const float4*)(gBg + k * 64);   // reg-only, before barrier
      float4 vu = *(const float4*)(gBu + k * 64);
      __syncthreads();                              // prev compute done
#pragma unroll
      for (int mt = 0; mt < GROUP; ++mt)
        if (mt < tg) {
          lds_load16(&As[mt][tid * 8],        gA0[mt] + k * 64);
          lds_load16(&As[mt][tid * 8 + 2048], gA1[mt] + k * 64);
        }
      *(bf16x4*)&BgS[br * 64 + wb] = cvt4(vg);
      *(bf16x4*)&BuS[br * 64 + wb] = cvt4(vu);
      __syncthreads();                              // staging visible
#pragma unroll
      for (int ks = 0; ks < 2; ++ks) {
        const int lch = ks * 4 + lquad;
        bf16x8 bg = *(const bf16x8*)&BgS[lcol * 64 + ((lch ^ (lcol & 7)) * 8)];
        bf16x8 bu = *(const bf16x8*)&BuS[lcol * 64 + ((lch ^ (lcol & 7)) * 8)];
        const int ar = wm + lcol;
        const int aoff = ar * 64 + ((lch ^ (ar & 7)) * 8);
#pragma unroll
        for (int mt = 0; mt < GROUP; ++mt)
          if (mt < tg) {
            bf16x8 af = *(const bf16x8*)&As[mt][aoff];
            aG[mt] = __builtin_amdgcn_mfma_f32_16x16x32_bf16(af, bg, aG[mt], 0, 0, 0);
            aU[mt] = __builtin_amdgcn_mfma_f32_16x16x32_bf16(af, bu, aU[mt], 0, 0, 0);
          }
      }
    }
    // epilogue: C/D col=lane&15, row=lquad*4+rr
#pragma unroll
    for (int mt = 0; mt < GROUP; ++mt)
      if (mt < tg) {
#pragma unroll
        for (int rr = 0; rr < 4; ++rr) {
          const int erow = (mg + 2 * mt) * 64 + wm + lquad * 4 + rr;
          const float wgt = ew[ebase + erow];
          float g = aG[mt][rr], u = aU[mt][rr];
          float s = g / (1.f + __expf(-g));
          hsc[(size_t)(ebase + erow) * IDIM + n0 + lcol] = (bf16)(s * u * wgt);
        }
      }
  }
}

// ---------------- GEMM2: slab[k][tok,h] = hsc[entry,:] . down[e,h,:] ----------------
// Same inversion + n-split to 16 H-channels (B rows disjoint) + z-parity m-split
// (A rows disjoint). Grid (64,16,2)=2048 blocks, LDS 26KB. Plain scatter stores.

__global__ __launch_bounds__(256, 4) void gemm2_kernel(
    const bf16* __restrict__ hsc,    // [E*CAP, I] bf16
    const float* __restrict__ down,  // [E,H,I] fp32
    const int* __restrict__ etk, const int* __restrict__ cntpad,
    float* __restrict__ slabs) {     // [4][(T+1)][H] fp32
  __shared__ __align__(16) bf16 As[GROUP][64 * 64];  // 24 KB
  __shared__ __align__(16) bf16 Bs[16 * 64];         // 2 KB
  const int e  = blockIdx.y;
  const int z  = blockIdx.z;
  const int trips = cntpad[e] >> 6;
  const int n0 = blockIdx.x * 16;
  const int ebase = e * CAP;
  const int tid = threadIdx.x, lane = tid & 63, wid = tid >> 6;
  const int wm = wid * 16;
  const int lcol = lane & 15, lquad = lane >> 4;
  const int srow = tid >> 3;
  const int swz  = ((tid & 7) ^ (srow & 7)) * 8;
  // B staging (R5 16-row pattern): br=tid>>4, bc=(tid&15)*4 fp32; half-chunk writes
  const int br = tid >> 4;
  const int bc = (tid & 15) * 4;
  const int wb = (((bc >> 3) ^ (br & 7)) * 8) + (bc & 7);
  const float* gB = down + (size_t)e * HDIM * IDIM + (size_t)(n0 + br) * IDIM + bc;

  for (int mg = z; mg < trips; mg += 2 * GROUP) {
    int tg = (trips - mg + 1) >> 1;
    if (tg > GROUP) tg = GROUP;
    const bf16 *gA0[GROUP], *gA1[GROUP];
#pragma unroll
    for (int mt = 0; mt < GROUP; ++mt)
      if (mt < tg) {
        const size_t rbase = (size_t)(ebase + (mg + 2 * mt) * 64);
        gA0[mt] = hsc + (rbase + srow) * IDIM + swz;
        gA1[mt] = hsc + (rbase + srow + 32) * IDIM + swz;
      }
    f32x4 acc[GROUP];
#pragma unroll
    for (int mt = 0; mt < GROUP; ++mt) acc[mt] = f32x4{0.f, 0.f, 0.f, 0.f};

    for (int k = 0; k < IDIM / 64; ++k) {
      float4 vb = *(const float4*)(gB + k * 64);
      __syncthreads();
#pragma unroll
      for (int mt = 0; mt < GROUP; ++mt)
        if (mt < tg) {
          lds_load16(&As[mt][tid * 8],        gA0[mt] + k * 64);
          lds_load16(&As[mt][tid * 8 + 2048], gA1[mt] + k * 64);
        }
      *(bf16x4*)&Bs[br * 64 + wb] = cvt4(vb);
      __syncthreads();
#pragma unroll
      for (int ks = 0; ks < 2; ++ks) {
        const int lch = ks * 4 + lquad;
        bf16x8 bv = *(const bf16x8*)&Bs[lcol * 64 + ((lch ^ (lcol & 7)) * 8)];
        const int ar = wm + lcol;
        const int aoff = ar * 64 + ((lch ^ (ar & 7)) * 8);
#pragma unroll
        for (int mt = 0; mt < GROUP; ++mt)
          if (mt < tg) {
            bf16x8 af = *(const bf16x8*)&As[mt][aoff];
            acc[mt] = __builtin_amdgcn_mfma_f32_16x16x32_bf16(af, bv, acc[mt], 0, 0, 0);
          }
      }
    }
    // epilogue: plain scatter stores (each (t,k) slab row written once per n-slice)
#pragma unroll
    for (int mt = 0; mt < GROUP; ++mt)
      if (mt < tg) {
#pragma unroll
        for (int rr = 0; rr < 4; ++rr) {
          const int tk = etk[ebase + (mg + 2 * mt) * 64 + wm + lquad * 4 + rr];
          const int tok = tk >> 2, kslot = tk & 3;
          slabs[((size_t)kslot * (T_TOK + 1) + tok) * HDIM + n0 + lcol] = acc[mt][rr];
        }
      }
  }
}

// ---------------- reduce: out = sum of 4 slabs ----------------

__global__ void reduce_kernel(const float* __restrict__ slabs, float* __restrict__ out) {
  const size_t stride = (size_t)(T_TOK + 1) * HDIM;
  int i = blockIdx.x * blockDim.x + threadIdx.x;
  float4 a = ((const float4*)slabs)[i];
  float4 b = ((const float4*)(slabs + stride))[i];
  float4 c = ((const float4*)(slabs + 2 * stride))[i];
  float4 d = ((const float4*)(slabs + 3 * stride))[i];
  float4 o;
  o.x = a.x + b.x + c.x + d.x;
  o.y = a.y + b.y + c.y + d.y;
  o.z = a.z + b.z + c.z + d.z;
  o.w = a.w + b.w + c.w + d.w;
  ((float4*)out)[i] = o;
}

// ---------------- launch ----------------

extern "C" void kernel_launch(void* const* d_in, const int* in_sizes, int n_in,
                              void* d_out, int out_size, void* d_ws, size_t ws_size,
                              hipStream_t stream) {
  const float* hid_f  = (const float*)d_in[0];
  const int*   idx    = (const int*)d_in[1];
  const float* tw     = (const float*)d_in[2];
  const float* gup_f  = (const float*)d_in[3];
  const float* down_f = (const float*)d_in[4];
  float* out = (float*)d_out;

  uint8_t* ws = (uint8_t*)d_ws;
  size_t off = 0;
  bf16* hid_b = (bf16*)(ws + off);   off += (size_t)(T_TOK + 1) * HDIM * 2;
  int*  etk   = (int*)(ws + off);    off += (size_t)NEXP * CAP * 4;
  float* ewt  = (float*)(ws + off);  off += (size_t)NEXP * CAP * 4;
  int* cntpad = (int*)(ws + off);    off += 256;
  bf16* hsc   = (bf16*)(ws + off);   off += (size_t)NEXP * CAP * IDIM * 2;
  float* slabs = (float*)(ws + off); // 4*(T+1)*H*4 ≈ 16.8 MB

  prep_kernel<<<dim3(CVT_BLOCKS + NEXP), dim3(256), 0, stream>>>(
      hid_f, hid_b, idx, tw, etk, ewt, cntpad);
  gemm1_kernel<<<dim3(IDIM / 16, NEXP, 2), dim3(256), 0, stream>>>(
      hid_b, gup_f, etk, ewt, cntpad, hsc);
  gemm2_kernel<<<dim3(HDIM / 16, NEXP, 2), dim3(256), 0, stream>>>(
      hsc, down_f, etk, cntpad, slabs);
  reduce_kernel<<<dim3(T_TOK * HDIM / 4 / 256), dim3(256), 0, stream>>>(slabs, out);
}